// Round 13
// baseline (417.018 us; speedup 1.0000x reference)
//
#include <hip/hip_runtime.h>
#include <hip/hip_bf16.h>

#define NN 100000
#define NE 800000
#define NCL 10000
#define CAPN 32   // max in-degree bucket (Poisson(8): P(>=32) ~ 1e-10)
#define CAPC 40   // max cluster size bucket (Poisson(10): P(>=40) ~ 6e-13)

typedef __attribute__((ext_vector_type(8))) short short8;
typedef __attribute__((ext_vector_type(4))) float f32x4;

__device__ __forceinline__ float bflo(unsigned int u) {
  return __uint_as_float(u << 16);
}
__device__ __forceinline__ float bfhi(unsigned int u) {
  return __uint_as_float(u & 0xffff0000u);
}
__device__ __forceinline__ unsigned short f2bf(float f) {
  unsigned int u = __float_as_uint(f);
  u += 0x7fffu + ((u >> 16) & 1u);
  return (unsigned short)(u >> 16);
}
__device__ __forceinline__ unsigned int packbf_exact(float lo, float hi) {
  return (__float_as_uint(lo) >> 16) | (__float_as_uint(hi) & 0xffff0000u);
}

// ---- fused front kernel: zero counters + weight transpose/convert ----
struct WtDesc { const float* src; unsigned short* dst; int rows, cols; };
struct WtPack { WtDesc d[6]; };
__global__ __launch_bounds__(256) void prep_kernel(int* zbase, int zn, int zblocks, WtPack p) {
  if ((int)blockIdx.x < zblocks) {
    int i = blockIdx.x * 256 + threadIdx.x;
    if (i < zn) zbase[i] = 0;
    return;
  }
  int b = blockIdx.x - zblocks;
  const long stride = 32L * 256;
  for (int a = 0; a < 6; ++a) {
    int rows = p.d[a].rows, cols = p.d[a].cols, n = rows * cols;
    const float* src = p.d[a].src;
    unsigned short* dst = p.d[a].dst;
    for (long i = (long)b * 256 + threadIdx.x; i < n; i += stride) {
      int r = (int)(i / cols), c = (int)(i % cols);
      dst[(long)c * rows + r] = f2bf(src[(long)r * cols + c]);
    }
  }
}

// ---- scatter body (device fn): bucket scatter, 4 items/thread (R10/R11) ----
__device__ __forceinline__ void scatter_body(
    int i,
    const int* __restrict__ ei, int* __restrict__ cnt, int* __restrict__ bucket,
    const int* __restrict__ cl, int* __restrict__ ccnt, int* __restrict__ cbucket) {
  if (i < NE / 4) {
    int4 t = reinterpret_cast<const int4*>(ei + NE)[i];
    int4 s = reinterpret_cast<const int4*>(ei)[i];
    int p0 = atomicAdd(&cnt[t.x], 1);
    int p1 = atomicAdd(&cnt[t.y], 1);
    int p2 = atomicAdd(&cnt[t.z], 1);
    int p3 = atomicAdd(&cnt[t.w], 1);
    if (p0 < CAPN) bucket[t.x * CAPN + p0] = s.x;
    if (p1 < CAPN) bucket[t.y * CAPN + p1] = s.y;
    if (p2 < CAPN) bucket[t.z * CAPN + p2] = s.z;
    if (p3 < CAPN) bucket[t.w * CAPN + p3] = s.w;
  } else if (i < NE / 4 + NN / 4) {
    int j = i - NE / 4;
    int4 c = reinterpret_cast<const int4*>(cl)[j];
    int n0 = j * 4;
    int p0 = atomicAdd(&ccnt[c.x], 1);
    int p1 = atomicAdd(&ccnt[c.y], 1);
    int p2 = atomicAdd(&ccnt[c.z], 1);
    int p3 = atomicAdd(&ccnt[c.w], 1);
    if (p0 < CAPC) cbucket[c.x * CAPC + p0] = n0;
    if (p1 < CAPC) cbucket[c.y * CAPC + p1] = n0 + 1;
    if (p2 < CAPC) cbucket[c.z * CAPC + p2] = n0 + 2;
    if (p3 < CAPC) cbucket[c.w * CAPC + p3] = n0 + 3;
  }
}

// ---- MFMA MLP: Linear(C->64) + LN + ReLU + Linear(64->C) ----
// Block = 4 waves; weights staged to LDS once per block (R8 win). Waves
// grid-stride over 16-node tiles, no barriers after staging.
// DO_SCATTER (layer 0): blocks [0,sblocks) run the independent bucket
// scatter, co-scheduled with the MLP (R12: small win, keep).
template<int C, bool INF32, bool DO_SCATTER>
__global__ __launch_bounds__(256) void mlp_mfma_kernel(
    const void* __restrict__ xin_v,
    const unsigned short* __restrict__ W1T,  // bf16 [64][C]
    const float* __restrict__ b1, const float* __restrict__ g, const float* __restrict__ be,
    const unsigned short* __restrict__ W2T,  // bf16 [C][64]
    const float* __restrict__ b2,
    unsigned short* __restrict__ out, int outstride, int ntiles,
    int sblocks,
    const int* __restrict__ ei, int* __restrict__ cnt, int* __restrict__ bucket,
    const int* __restrict__ cl, int* __restrict__ ccnt, int* __restrict__ cbucket)
{
  constexpr int CP = C + 8;
  __shared__ unsigned short w1s[64 * CP];   // [64][C+8]
  __shared__ unsigned short w2s[C * 72];    // [C][72] (64 used + pad)
  __shared__ unsigned short ps[4 * 16 * 72];
  int tid = threadIdx.x;

  if constexpr (DO_SCATTER) {
    if ((int)blockIdx.x < sblocks) {
      scatter_body(blockIdx.x * 256 + tid, ei, cnt, bucket, cl, ccnt, cbucket);
      return;
    }
  }
  int bid = blockIdx.x - (DO_SCATTER ? sblocks : 0);
  int mgrid = gridDim.x - (DO_SCATTER ? sblocks : 0);

  for (int i = tid; i < 64 * (C / 8); i += 256) {
    int r = i / (C / 8), cc = i % (C / 8);
    *reinterpret_cast<uint4*>(&w1s[r * CP + cc * 8]) =
        *reinterpret_cast<const uint4*>(W1T + r * C + cc * 8);
  }
  for (int i = tid; i < C * 8; i += 256) {
    int r = i / 8, cc = i % 8;
    *reinterpret_cast<uint4*>(&w2s[r * 72 + cc * 8]) =
        *reinterpret_cast<const uint4*>(W2T + r * 64 + cc * 8);
  }
  __syncthreads();

  int wv = tid >> 6, lane = tid & 63;
  int l15 = lane & 15, q = lane >> 4;
  unsigned short* psw = &ps[wv * 16 * 72];

  float b1v[4], gv[4], bev[4];
  #pragma unroll
  for (int t = 0; t < 4; ++t) {
    b1v[t] = b1[t * 16 + l15];
    gv[t]  = g[t * 16 + l15];
    bev[t] = be[t * 16 + l15];
  }
  constexpr int NT2 = C / 16;
  float b2v[NT2];
  #pragma unroll
  for (int tc = 0; tc < NT2; ++tc) b2v[tc] = b2[tc * 16 + l15];

  for (long tile = (long)bid * 4 + wv; tile < ntiles; tile += (long)mgrid * 4) {
    long nb = tile * 16;
    long arow = nb + l15;

    f32x4 acc[4];
    #pragma unroll
    for (int t = 0; t < 4; ++t) acc[t] = (f32x4){0.f, 0.f, 0.f, 0.f};
    #pragma unroll
    for (int kk = 0; kk < C / 32; ++kk) {
      short8 a;
      if constexpr (INF32) {
        const float* xf = (const float*)xin_v;
        const float* src = xf + arow * C + kk * 32 + q * 8;
        float4 v0 = reinterpret_cast<const float4*>(src)[0];
        float4 v1 = reinterpret_cast<const float4*>(src)[1];
        a[0] = (short)f2bf(v0.x); a[1] = (short)f2bf(v0.y);
        a[2] = (short)f2bf(v0.z); a[3] = (short)f2bf(v0.w);
        a[4] = (short)f2bf(v1.x); a[5] = (short)f2bf(v1.y);
        a[6] = (short)f2bf(v1.z); a[7] = (short)f2bf(v1.w);
      } else {
        const unsigned short* xh = (const unsigned short*)xin_v;
        a = *reinterpret_cast<const short8*>(xh + arow * C + kk * 32 + q * 8);
      }
      #pragma unroll
      for (int t = 0; t < 4; ++t) {
        short8 b = *reinterpret_cast<const short8*>(&w1s[(t * 16 + l15) * CP + kk * 32 + q * 8]);
        acc[t] = __builtin_amdgcn_mfma_f32_16x16x32_bf16(a, b, acc[t], 0, 0, 0);
      }
    }

    float vout[4][4];
    #pragma unroll
    for (int r = 0; r < 4; ++r) {
      float h0 = acc[0][r] + b1v[0];
      float h1 = acc[1][r] + b1v[1];
      float h2 = acc[2][r] + b1v[2];
      float h3 = acc[3][r] + b1v[3];
      float s = (h0 + h1) + (h2 + h3);
      s += __shfl_xor(s, 1); s += __shfl_xor(s, 2);
      s += __shfl_xor(s, 4); s += __shfl_xor(s, 8);
      float mu = s * (1.0f / 64.0f);
      float d0 = h0 - mu, d1 = h1 - mu, d2 = h2 - mu, d3 = h3 - mu;
      float qs = (d0 * d0 + d1 * d1) + (d2 * d2 + d3 * d3);
      qs += __shfl_xor(qs, 1); qs += __shfl_xor(qs, 2);
      qs += __shfl_xor(qs, 4); qs += __shfl_xor(qs, 8);
      float rinv = rsqrtf(qs * (1.0f / 64.0f) + 1e-5f);
      vout[0][r] = fmaxf(0.f, d0 * rinv * gv[0] + bev[0]);
      vout[1][r] = fmaxf(0.f, d1 * rinv * gv[1] + bev[1]);
      vout[2][r] = fmaxf(0.f, d2 * rinv * gv[2] + bev[2]);
      vout[3][r] = fmaxf(0.f, d3 * rinv * gv[3] + bev[3]);
    }

    #pragma unroll
    for (int t = 0; t < 4; ++t)
      #pragma unroll
      for (int r = 0; r < 4; ++r)
        psw[(q * 4 + r) * 72 + t * 16 + l15] = f2bf(vout[t][r]);

    short8 a0 = *reinterpret_cast<const short8*>(&psw[l15 * 72 + q * 8]);
    short8 a1 = *reinterpret_cast<const short8*>(&psw[l15 * 72 + 32 + q * 8]);
    long node0 = nb + q * 4;
    #pragma unroll
    for (int tc = 0; tc < NT2; ++tc) {
      short8 b0 = *reinterpret_cast<const short8*>(&w2s[(tc * 16 + l15) * 72 + q * 8]);
      short8 b1w = *reinterpret_cast<const short8*>(&w2s[(tc * 16 + l15) * 72 + 32 + q * 8]);
      f32x4 c = (f32x4){0.f, 0.f, 0.f, 0.f};
      c = __builtin_amdgcn_mfma_f32_16x16x32_bf16(a0, b0, c, 0, 0, 0);
      c = __builtin_amdgcn_mfma_f32_16x16x32_bf16(a1, b1w, c, 0, 0, 0);
      #pragma unroll
      for (int r = 0; r < 4; ++r)
        out[(node0 + r) * (long)outstride + tc * 16 + l15] = f2bf(c[r] + b2v[tc]);
    }
  }
}

// ---- per-target max aggregation over bucket edge lists (bf16 storage) ----
// 4-way unrolled (R9 win; 8-way regressed via VGPR pressure).
template<int C>
__global__ __launch_bounds__(256) void aggr_kernel(
    const int* __restrict__ cnt, const int* __restrict__ bucket,
    unsigned short* __restrict__ xnext)
{
  constexpr int Q = C / 8;
  constexpr int NPB = 256 / Q;
  int q = threadIdx.x & (Q - 1);
  int ln = threadIdx.x / Q;
  long node = (long)blockIdx.x * NPB + ln;
  int end = min(cnt[node], CAPN);
  const int* bl = bucket + node * CAPN;
  float m[8];
  #pragma unroll
  for (int k = 0; k < 8; ++k) m[k] = -3.4e38f;

  auto acc8 = [&](uint4 u) {
    m[0] = fmaxf(m[0], bflo(u.x)); m[1] = fmaxf(m[1], bfhi(u.x));
    m[2] = fmaxf(m[2], bflo(u.y)); m[3] = fmaxf(m[3], bfhi(u.y));
    m[4] = fmaxf(m[4], bflo(u.z)); m[5] = fmaxf(m[5], bfhi(u.z));
    m[6] = fmaxf(m[6], bflo(u.w)); m[7] = fmaxf(m[7], bfhi(u.w));
  };
  auto row = [&](int s) {
    return reinterpret_cast<const uint4*>(xnext + (long)s * (2 * C))[q];
  };

  int e = 0;
  for (; e + 3 < end; e += 4) {
    int s0 = bl[e], s1 = bl[e + 1], s2 = bl[e + 2], s3 = bl[e + 3];
    uint4 u0 = row(s0), u1 = row(s1), u2 = row(s2), u3 = row(s3);
    acc8(u0); acc8(u1); acc8(u2); acc8(u3);
  }
  for (; e < end; ++e) acc8(row(bl[e]));
  if (end == 0) {
    #pragma unroll
    for (int k = 0; k < 8; ++k) m[k] = 0.f;
  }
  uint4 o;
  o.x = packbf_exact(m[0], m[1]);
  o.y = packbf_exact(m[2], m[3]);
  o.z = packbf_exact(m[4], m[5]);
  o.w = packbf_exact(m[6], m[7]);
  reinterpret_cast<uint4*>(xnext + (long)node * (2 * C) + C)[q] = o;
}

// ---- fused layer-3 aggregation + cluster max-pool (R13) ----
// pooled[k] = concat( max_{n in k} h3[n],  max_{n in k} aggr3[n] ) where
// aggr3[n] = (deg>0 ? max_{src} h3[src] : 0). max commutes with concat, so
// the per-node aggr halves are never materialized -- saves the 51MB aggr
// write + 51MB pool re-read + one dispatch. h3 is compact [N,256] bf16.
__global__ __launch_bounds__(256) void poolfuse_kernel(
    const int* __restrict__ ccnt, const int* __restrict__ cbucket,
    const int* __restrict__ cnt, const int* __restrict__ bucket,
    const unsigned short* __restrict__ h3, float* __restrict__ pooled)
{
  int q = threadIdx.x & 31;        // 32 uint4 chunks of a 256-bf16 row
  int lc = threadIdx.x >> 5;       // 8 clusters per block
  long k = (long)blockIdx.x * 8 + lc;
  int cend = min(ccnt[k], CAPC);
  const int* cbl = cbucket + k * CAPC;

  float mL[8], mR[8];
  #pragma unroll
  for (int t = 0; t < 8; ++t) { mL[t] = -3.4e38f; mR[t] = -3.4e38f; }

  auto fold = [](float* m, uint4 u) {
    m[0] = fmaxf(m[0], bflo(u.x)); m[1] = fmaxf(m[1], bfhi(u.x));
    m[2] = fmaxf(m[2], bflo(u.y)); m[3] = fmaxf(m[3], bfhi(u.y));
    m[4] = fmaxf(m[4], bflo(u.z)); m[5] = fmaxf(m[5], bfhi(u.z));
    m[6] = fmaxf(m[6], bflo(u.w)); m[7] = fmaxf(m[7], bfhi(u.w));
  };
  auto row = [&](int n) {
    return reinterpret_cast<const uint4*>(h3 + (long)n * 256)[q];
  };

  for (int i = 0; i < cend; ++i) {
    int n = cbl[i];
    fold(mL, row(n));
    int ee = min(cnt[n], CAPN);
    const int* bl = bucket + (long)n * CAPN;
    float nm[8];
    #pragma unroll
    for (int t = 0; t < 8; ++t) nm[t] = -3.4e38f;
    int e = 0;
    for (; e + 3 < ee; e += 4) {
      int s0 = bl[e], s1 = bl[e + 1], s2 = bl[e + 2], s3 = bl[e + 3];
      uint4 u0 = row(s0), u1 = row(s1), u2 = row(s2), u3 = row(s3);
      fold(nm, u0); fold(nm, u1); fold(nm, u2); fold(nm, u3);
    }
    for (; e < ee; ++e) fold(nm, row(bl[e]));
    if (ee == 0) {
      #pragma unroll
      for (int t = 0; t < 8; ++t) nm[t] = 0.f;   // edgeless node -> aggr = 0
    }
    #pragma unroll
    for (int t = 0; t < 8; ++t) mR[t] = fmaxf(mR[t], nm[t]);
  }
  if (cend == 0) {
    #pragma unroll
    for (int t = 0; t < 8; ++t) { mL[t] = 0.f; mR[t] = 0.f; }
  }
  float* oL = pooled + k * 512 + q * 8;
  float* oR = oL + 256;
  reinterpret_cast<float4*>(oL)[0] = make_float4(mL[0], mL[1], mL[2], mL[3]);
  reinterpret_cast<float4*>(oL)[1] = make_float4(mL[4], mL[5], mL[6], mL[7]);
  reinterpret_cast<float4*>(oR)[0] = make_float4(mR[0], mR[1], mR[2], mR[3]);
  reinterpret_cast<float4*>(oR)[1] = make_float4(mR[4], mR[5], mR[6], mR[7]);
}

__global__ __launch_bounds__(256) void colnorm_kernel(const float* __restrict__ pooled,
                                                      float* __restrict__ normsq) {
  int tid = threadIdx.x;
  int rows_per = (NCL + gridDim.x - 1) / gridDim.x;
  int r0 = blockIdx.x * rows_per;
  int r1 = min(r0 + rows_per, NCL);
  float s0 = 0.f, s1 = 0.f;
  for (int r = r0; r < r1; ++r) {
    float a = pooled[(long)r * 512 + tid];
    float b = pooled[(long)r * 512 + 256 + tid];
    s0 = fmaf(a, a, s0);
    s1 = fmaf(b, b, s1);
  }
  atomicAdd(&normsq[tid], s0);
  atomicAdd(&normsq[tid + 256], s1);
}

__global__ __launch_bounds__(256) void normalize_kernel(const float* __restrict__ pooled,
                                                        const float* __restrict__ normsq,
                                                        float* __restrict__ out) {
  long idx = (long)blockIdx.x * 256 + threadIdx.x;
  if (idx < (long)NCL * 512) {
    float nv = normsq[idx & 511];
    out[idx] = pooled[idx] * rsqrtf(nv);
  }
}

extern "C" void kernel_launch(void* const* d_in, const int* in_sizes, int n_in,
                              void* d_out, int out_size, void* d_ws, size_t ws_size,
                              hipStream_t stream) {
  const float* x0 = (const float*)d_in[0];
  const int* ei = (const int*)d_in[1];
  const int* cl = (const int*)d_in[2];

  const float* W1f[3]; const float* b1f[3]; const float* gf[3];
  const float* bef[3]; const float* W2f[3]; const float* b2f[3];
  for (int i = 0; i < 3; ++i) {
    W1f[i] = (const float*)d_in[3 + 6 * i + 0];
    b1f[i] = (const float*)d_in[3 + 6 * i + 1];
    gf[i]  = (const float*)d_in[3 + 6 * i + 2];
    bef[i] = (const float*)d_in[3 + 6 * i + 3];
    W2f[i] = (const float*)d_in[3 + 6 * i + 4];
    b2f[i] = (const float*)d_in[3 + 6 * i + 5];
  }

  char* ws = (char*)d_ws;
  size_t off = 0;
  auto take = [&](size_t bytes) {
    size_t o = off; off = (off + bytes + 255) & ~(size_t)255; return o;
  };
  // region R1: x1 [N,128] bf16 (layer0/1), later x3c [N,256] bf16 (x1 dead
  // once mlp<128> has consumed it; mlp<256> then writes x3c here).
  unsigned short* x1 = (unsigned short*)(ws + take((size_t)NN * 256 * 2));
  unsigned short* x3c = x1;
  // region R2: x2 [N,256] bf16 (layers 1/2), later pooled [NC,512] fp32
  // (x2 dead after mlp<256> reads it; poolfuse writes pooled here).
  unsigned short* x2 = (unsigned short*)(ws + take((size_t)NN * 256 * 2));
  float* pooled = (float*)x2;
  // bucket must stay live through poolfuse -> own region (NOT aliased).
  int* bucket = (int*)(ws + take((size_t)NN * CAPN * 4));
  int* cbucket = (int*)(ws + take((size_t)NCL * CAPC * 4));
  int* zero_base = (int*)(ws + take((size_t)(NN + NCL + 512) * 4));
  int* cnt = zero_base;
  int* ccnt = zero_base + NN;
  float* normsq = (float*)(zero_base + NN + NCL);

  int Cs[3] = {64, 128, 256};
  unsigned short *W1T[3], *W2T[3];
  for (int i = 0; i < 3; ++i) {
    W1T[i] = (unsigned short*)(ws + take((size_t)64 * Cs[i] * 2));
    W2T[i] = (unsigned short*)(ws + take((size_t)Cs[i] * 64 * 2));
  }

  if (off > ws_size) return;  // clean-fail guard

  WtPack wp;
  for (int i = 0; i < 3; ++i) {
    wp.d[2 * i + 0] = { W1f[i], W1T[i], Cs[i], 64 };
    wp.d[2 * i + 1] = { W2f[i], W2T[i], 64, Cs[i] };
  }

  int zn = NN + NCL + 512;
  int zblocks = (zn + 255) / 256;
  prep_kernel<<<zblocks + 32, 256, 0, stream>>>(zero_base, zn, zblocks, wp);

  int ntiles = NN / 16;            // 6250 (exact: no tail)
  int nblk = (ntiles / 2 + 3) / 4; // 782 mlp blocks x 4 waves x 2 tiles
  int nwork = NE / 4 + NN / 4;
  int sblocks = (nwork + 255) / 256;  // 879 scatter blocks

  // fused: scatter (blocks [0,sblocks)) + mlp layer 0 (rest)
  mlp_mfma_kernel<64, true, true><<<sblocks + nblk, 256, 0, stream>>>(
      x0, W1T[0], b1f[0], gf[0], bef[0], W2T[0], b2f[0], x1, 128, ntiles,
      sblocks, ei, cnt, bucket, cl, ccnt, cbucket);
  aggr_kernel<64><<<NN / 32, 256, 0, stream>>>(cnt, bucket, x1);
  mlp_mfma_kernel<128, false, false><<<nblk, 256, 0, stream>>>(
      x1, W1T[1], b1f[1], gf[1], bef[1], W2T[1], b2f[1], x2, 256, ntiles,
      0, nullptr, nullptr, nullptr, nullptr, nullptr, nullptr);
  aggr_kernel<128><<<NN / 16, 256, 0, stream>>>(cnt, bucket, x2);
  // layer 2 writes compact h3 [N,256] (no aggr half materialized)
  mlp_mfma_kernel<256, false, false><<<nblk, 256, 0, stream>>>(
      x2, W1T[2], b1f[2], gf[2], bef[2], W2T[2], b2f[2], x3c, 256, ntiles,
      0, nullptr, nullptr, nullptr, nullptr, nullptr, nullptr);

  // fused aggr<256> + cluster max-pool
  poolfuse_kernel<<<NCL / 8, 256, 0, stream>>>(ccnt, cbucket, cnt, bucket, x3c, pooled);
  colnorm_kernel<<<128, 256, 0, stream>>>(pooled, normsq);
  normalize_kernel<<<((long)NCL * 512 + 255) / 256, 256, 0, stream>>>(pooled, normsq, (float*)d_out);
}

// Round 14
// 395.486 us; speedup vs baseline: 1.0544x; 1.0544x over previous
//
#include <hip/hip_runtime.h>
#include <hip/hip_bf16.h>

#define NN 100000
#define NE 800000
#define NCL 10000
#define CAPN 32   // max in-degree bucket (Poisson(8): P(>=32) ~ 1e-10)
#define CAPC 40   // max cluster size bucket (Poisson(10): P(>=40) ~ 6e-13)

typedef __attribute__((ext_vector_type(8))) short short8;
typedef __attribute__((ext_vector_type(4))) float f32x4;

__device__ __forceinline__ float bflo(unsigned int u) {
  return __uint_as_float(u << 16);
}
__device__ __forceinline__ float bfhi(unsigned int u) {
  return __uint_as_float(u & 0xffff0000u);
}
__device__ __forceinline__ unsigned short f2bf(float f) {
  unsigned int u = __float_as_uint(f);
  u += 0x7fffu + ((u >> 16) & 1u);
  return (unsigned short)(u >> 16);
}
__device__ __forceinline__ unsigned int packbf_exact(float lo, float hi) {
  return (__float_as_uint(lo) >> 16) | (__float_as_uint(hi) & 0xffff0000u);
}

// ---- fused front kernel: zero counters + weight transpose/convert ----
struct WtDesc { const float* src; unsigned short* dst; int rows, cols; };
struct WtPack { WtDesc d[6]; };
__global__ __launch_bounds__(256) void prep_kernel(int* zbase, int zn, int zblocks, WtPack p) {
  if ((int)blockIdx.x < zblocks) {
    int i = blockIdx.x * 256 + threadIdx.x;
    if (i < zn) zbase[i] = 0;
    return;
  }
  int b = blockIdx.x - zblocks;
  const long stride = 32L * 256;
  for (int a = 0; a < 6; ++a) {
    int rows = p.d[a].rows, cols = p.d[a].cols, n = rows * cols;
    const float* src = p.d[a].src;
    unsigned short* dst = p.d[a].dst;
    for (long i = (long)b * 256 + threadIdx.x; i < n; i += stride) {
      int r = (int)(i / cols), c = (int)(i % cols);
      dst[(long)c * rows + r] = f2bf(src[(long)r * cols + c]);
    }
  }
}

// ---- scatter body (device fn): bucket scatter, 4 items/thread (R10/R11) ----
__device__ __forceinline__ void scatter_body(
    int i,
    const int* __restrict__ ei, int* __restrict__ cnt, int* __restrict__ bucket,
    const int* __restrict__ cl, int* __restrict__ ccnt, int* __restrict__ cbucket) {
  if (i < NE / 4) {
    int4 t = reinterpret_cast<const int4*>(ei + NE)[i];
    int4 s = reinterpret_cast<const int4*>(ei)[i];
    int p0 = atomicAdd(&cnt[t.x], 1);
    int p1 = atomicAdd(&cnt[t.y], 1);
    int p2 = atomicAdd(&cnt[t.z], 1);
    int p3 = atomicAdd(&cnt[t.w], 1);
    if (p0 < CAPN) bucket[t.x * CAPN + p0] = s.x;
    if (p1 < CAPN) bucket[t.y * CAPN + p1] = s.y;
    if (p2 < CAPN) bucket[t.z * CAPN + p2] = s.z;
    if (p3 < CAPN) bucket[t.w * CAPN + p3] = s.w;
  } else if (i < NE / 4 + NN / 4) {
    int j = i - NE / 4;
    int4 c = reinterpret_cast<const int4*>(cl)[j];
    int n0 = j * 4;
    int p0 = atomicAdd(&ccnt[c.x], 1);
    int p1 = atomicAdd(&ccnt[c.y], 1);
    int p2 = atomicAdd(&ccnt[c.z], 1);
    int p3 = atomicAdd(&ccnt[c.w], 1);
    if (p0 < CAPC) cbucket[c.x * CAPC + p0] = n0;
    if (p1 < CAPC) cbucket[c.y * CAPC + p1] = n0 + 1;
    if (p2 < CAPC) cbucket[c.z * CAPC + p2] = n0 + 2;
    if (p3 < CAPC) cbucket[c.w * CAPC + p3] = n0 + 3;
  }
}

// ---- MFMA MLP: Linear(C->64) + LN + ReLU + Linear(64->C) ----
// Block = 4 waves; weights staged to LDS once per block (R8 win). Waves
// grid-stride over 16-node tiles, no barriers after staging.
// DO_SCATTER (layer 0): blocks [0,sblocks) run the independent bucket
// scatter, co-scheduled with the MLP (R12: small win, keep).
template<int C, bool INF32, bool DO_SCATTER>
__global__ __launch_bounds__(256) void mlp_mfma_kernel(
    const void* __restrict__ xin_v,
    const unsigned short* __restrict__ W1T,  // bf16 [64][C]
    const float* __restrict__ b1, const float* __restrict__ g, const float* __restrict__ be,
    const unsigned short* __restrict__ W2T,  // bf16 [C][64]
    const float* __restrict__ b2,
    unsigned short* __restrict__ out, int outstride, int ntiles,
    int sblocks,
    const int* __restrict__ ei, int* __restrict__ cnt, int* __restrict__ bucket,
    const int* __restrict__ cl, int* __restrict__ ccnt, int* __restrict__ cbucket)
{
  constexpr int CP = C + 8;
  __shared__ unsigned short w1s[64 * CP];   // [64][C+8]
  __shared__ unsigned short w2s[C * 72];    // [C][72] (64 used + pad)
  __shared__ unsigned short ps[4 * 16 * 72];
  int tid = threadIdx.x;

  if constexpr (DO_SCATTER) {
    if ((int)blockIdx.x < sblocks) {
      scatter_body(blockIdx.x * 256 + tid, ei, cnt, bucket, cl, ccnt, cbucket);
      return;
    }
  }
  int bid = blockIdx.x - (DO_SCATTER ? sblocks : 0);
  int mgrid = gridDim.x - (DO_SCATTER ? sblocks : 0);

  for (int i = tid; i < 64 * (C / 8); i += 256) {
    int r = i / (C / 8), cc = i % (C / 8);
    *reinterpret_cast<uint4*>(&w1s[r * CP + cc * 8]) =
        *reinterpret_cast<const uint4*>(W1T + r * C + cc * 8);
  }
  for (int i = tid; i < C * 8; i += 256) {
    int r = i / 8, cc = i % 8;
    *reinterpret_cast<uint4*>(&w2s[r * 72 + cc * 8]) =
        *reinterpret_cast<const uint4*>(W2T + r * 64 + cc * 8);
  }
  __syncthreads();

  int wv = tid >> 6, lane = tid & 63;
  int l15 = lane & 15, q = lane >> 4;
  unsigned short* psw = &ps[wv * 16 * 72];

  float b1v[4], gv[4], bev[4];
  #pragma unroll
  for (int t = 0; t < 4; ++t) {
    b1v[t] = b1[t * 16 + l15];
    gv[t]  = g[t * 16 + l15];
    bev[t] = be[t * 16 + l15];
  }
  constexpr int NT2 = C / 16;
  float b2v[NT2];
  #pragma unroll
  for (int tc = 0; tc < NT2; ++tc) b2v[tc] = b2[tc * 16 + l15];

  for (long tile = (long)bid * 4 + wv; tile < ntiles; tile += (long)mgrid * 4) {
    long nb = tile * 16;
    long arow = nb + l15;

    f32x4 acc[4];
    #pragma unroll
    for (int t = 0; t < 4; ++t) acc[t] = (f32x4){0.f, 0.f, 0.f, 0.f};
    #pragma unroll
    for (int kk = 0; kk < C / 32; ++kk) {
      short8 a;
      if constexpr (INF32) {
        const float* xf = (const float*)xin_v;
        const float* src = xf + arow * C + kk * 32 + q * 8;
        float4 v0 = reinterpret_cast<const float4*>(src)[0];
        float4 v1 = reinterpret_cast<const float4*>(src)[1];
        a[0] = (short)f2bf(v0.x); a[1] = (short)f2bf(v0.y);
        a[2] = (short)f2bf(v0.z); a[3] = (short)f2bf(v0.w);
        a[4] = (short)f2bf(v1.x); a[5] = (short)f2bf(v1.y);
        a[6] = (short)f2bf(v1.z); a[7] = (short)f2bf(v1.w);
      } else {
        const unsigned short* xh = (const unsigned short*)xin_v;
        a = *reinterpret_cast<const short8*>(xh + arow * C + kk * 32 + q * 8);
      }
      #pragma unroll
      for (int t = 0; t < 4; ++t) {
        short8 b = *reinterpret_cast<const short8*>(&w1s[(t * 16 + l15) * CP + kk * 32 + q * 8]);
        acc[t] = __builtin_amdgcn_mfma_f32_16x16x32_bf16(a, b, acc[t], 0, 0, 0);
      }
    }

    float vout[4][4];
    #pragma unroll
    for (int r = 0; r < 4; ++r) {
      float h0 = acc[0][r] + b1v[0];
      float h1 = acc[1][r] + b1v[1];
      float h2 = acc[2][r] + b1v[2];
      float h3 = acc[3][r] + b1v[3];
      float s = (h0 + h1) + (h2 + h3);
      s += __shfl_xor(s, 1); s += __shfl_xor(s, 2);
      s += __shfl_xor(s, 4); s += __shfl_xor(s, 8);
      float mu = s * (1.0f / 64.0f);
      float d0 = h0 - mu, d1 = h1 - mu, d2 = h2 - mu, d3 = h3 - mu;
      float qs = (d0 * d0 + d1 * d1) + (d2 * d2 + d3 * d3);
      qs += __shfl_xor(qs, 1); qs += __shfl_xor(qs, 2);
      qs += __shfl_xor(qs, 4); qs += __shfl_xor(qs, 8);
      float rinv = rsqrtf(qs * (1.0f / 64.0f) + 1e-5f);
      vout[0][r] = fmaxf(0.f, d0 * rinv * gv[0] + bev[0]);
      vout[1][r] = fmaxf(0.f, d1 * rinv * gv[1] + bev[1]);
      vout[2][r] = fmaxf(0.f, d2 * rinv * gv[2] + bev[2]);
      vout[3][r] = fmaxf(0.f, d3 * rinv * gv[3] + bev[3]);
    }

    #pragma unroll
    for (int t = 0; t < 4; ++t)
      #pragma unroll
      for (int r = 0; r < 4; ++r)
        psw[(q * 4 + r) * 72 + t * 16 + l15] = f2bf(vout[t][r]);

    short8 a0 = *reinterpret_cast<const short8*>(&psw[l15 * 72 + q * 8]);
    short8 a1 = *reinterpret_cast<const short8*>(&psw[l15 * 72 + 32 + q * 8]);
    long node0 = nb + q * 4;
    #pragma unroll
    for (int tc = 0; tc < NT2; ++tc) {
      short8 b0 = *reinterpret_cast<const short8*>(&w2s[(tc * 16 + l15) * 72 + q * 8]);
      short8 b1w = *reinterpret_cast<const short8*>(&w2s[(tc * 16 + l15) * 72 + 32 + q * 8]);
      f32x4 c = (f32x4){0.f, 0.f, 0.f, 0.f};
      c = __builtin_amdgcn_mfma_f32_16x16x32_bf16(a0, b0, c, 0, 0, 0);
      c = __builtin_amdgcn_mfma_f32_16x16x32_bf16(a1, b1w, c, 0, 0, 0);
      #pragma unroll
      for (int r = 0; r < 4; ++r)
        out[(node0 + r) * (long)outstride + tc * 16 + l15] = f2bf(c[r] + b2v[tc]);
    }
  }
}

// ---- per-target max aggregation over bucket edge lists (bf16 storage) ----
// 4-way unrolled (R9 win; 8-way regressed via VGPR pressure).
template<int C>
__global__ __launch_bounds__(256) void aggr_kernel(
    const int* __restrict__ cnt, const int* __restrict__ bucket,
    unsigned short* __restrict__ xnext)
{
  constexpr int Q = C / 8;
  constexpr int NPB = 256 / Q;
  int q = threadIdx.x & (Q - 1);
  int ln = threadIdx.x / Q;
  long node = (long)blockIdx.x * NPB + ln;
  int end = min(cnt[node], CAPN);
  const int* bl = bucket + node * CAPN;
  float m[8];
  #pragma unroll
  for (int k = 0; k < 8; ++k) m[k] = -3.4e38f;

  auto acc8 = [&](uint4 u) {
    m[0] = fmaxf(m[0], bflo(u.x)); m[1] = fmaxf(m[1], bfhi(u.x));
    m[2] = fmaxf(m[2], bflo(u.y)); m[3] = fmaxf(m[3], bfhi(u.y));
    m[4] = fmaxf(m[4], bflo(u.z)); m[5] = fmaxf(m[5], bfhi(u.z));
    m[6] = fmaxf(m[6], bflo(u.w)); m[7] = fmaxf(m[7], bfhi(u.w));
  };
  auto row = [&](int s) {
    return reinterpret_cast<const uint4*>(xnext + (long)s * (2 * C))[q];
  };

  int e = 0;
  for (; e + 3 < end; e += 4) {
    int s0 = bl[e], s1 = bl[e + 1], s2 = bl[e + 2], s3 = bl[e + 3];
    uint4 u0 = row(s0), u1 = row(s1), u2 = row(s2), u3 = row(s3);
    acc8(u0); acc8(u1); acc8(u2); acc8(u3);
  }
  for (; e < end; ++e) acc8(row(bl[e]));
  if (end == 0) {
    #pragma unroll
    for (int k = 0; k < 8; ++k) m[k] = 0.f;
  }
  uint4 o;
  o.x = packbf_exact(m[0], m[1]);
  o.y = packbf_exact(m[2], m[3]);
  o.z = packbf_exact(m[4], m[5]);
  o.w = packbf_exact(m[6], m[7]);
  reinterpret_cast<uint4*>(xnext + (long)node * (2 * C) + C)[q] = o;
}

// ---- fused layer-3 aggr + cluster max-pool, v2 (R14) ----
// R13 fused correctly (traffic dropped) but lost 8x parallelism. v2:
// one block PER CLUSTER (10000 blocks); 8 groups of 32 lanes take the
// cluster's nodes strided; per-group partial maxes reduce through LDS.
// pooled[k] = concat(max_n h3[n], max_n aggr3[n]); aggr3 from buckets,
// edgeless node -> 0; empty cluster -> 0.
__global__ __launch_bounds__(256) void poolfuse_kernel(
    const int* __restrict__ ccnt, const int* __restrict__ cbucket,
    const int* __restrict__ cnt, const int* __restrict__ bucket,
    const unsigned short* __restrict__ h3, float* __restrict__ pooled)
{
  __shared__ float redL[8][256];
  __shared__ float redR[8][256];
  int tid = threadIdx.x;
  int q = tid & 31;          // 32 uint4 chunks of a 256-bf16 row
  int g = tid >> 5;          // node-worker group 0..7
  long k = blockIdx.x;       // one cluster per block
  int cend = min(ccnt[k], CAPC);
  const int* cbl = cbucket + k * CAPC;

  float mL[8], mR[8];
  #pragma unroll
  for (int t = 0; t < 8; ++t) { mL[t] = -3.4e38f; mR[t] = -3.4e38f; }

  auto fold = [](float* m, uint4 u) {
    m[0] = fmaxf(m[0], bflo(u.x)); m[1] = fmaxf(m[1], bfhi(u.x));
    m[2] = fmaxf(m[2], bflo(u.y)); m[3] = fmaxf(m[3], bfhi(u.y));
    m[4] = fmaxf(m[4], bflo(u.z)); m[5] = fmaxf(m[5], bfhi(u.z));
    m[6] = fmaxf(m[6], bflo(u.w)); m[7] = fmaxf(m[7], bfhi(u.w));
  };
  auto row = [&](int n) {
    return reinterpret_cast<const uint4*>(h3 + (long)n * 256)[q];
  };

  for (int i = g; i < cend; i += 8) {
    int n = cbl[i];
    fold(mL, row(n));
    int ee = min(cnt[n], CAPN);
    const int* bl = bucket + (long)n * CAPN;
    float nm[8];
    #pragma unroll
    for (int t = 0; t < 8; ++t) nm[t] = -3.4e38f;
    int e = 0;
    for (; e + 3 < ee; e += 4) {
      int s0 = bl[e], s1 = bl[e + 1], s2 = bl[e + 2], s3 = bl[e + 3];
      uint4 u0 = row(s0), u1 = row(s1), u2 = row(s2), u3 = row(s3);
      fold(nm, u0); fold(nm, u1); fold(nm, u2); fold(nm, u3);
    }
    for (; e < ee; ++e) fold(nm, row(bl[e]));
    if (ee == 0) {
      #pragma unroll
      for (int t = 0; t < 8; ++t) nm[t] = 0.f;   // edgeless node -> aggr = 0
    }
    #pragma unroll
    for (int t = 0; t < 8; ++t) mR[t] = fmaxf(mR[t], nm[t]);
  }

  #pragma unroll
  for (int t = 0; t < 8; ++t) {
    redL[g][q * 8 + t] = mL[t];
    redR[g][q * 8 + t] = mR[t];
  }
  __syncthreads();

  // cross-group reduce: thread tid owns channel c = tid (256 channels/side)
  int c = tid;
  float vL = redL[0][c], vR = redR[0][c];
  #pragma unroll
  for (int gg = 1; gg < 8; ++gg) {
    vL = fmaxf(vL, redL[gg][c]);
    vR = fmaxf(vR, redR[gg][c]);
  }
  if (cend == 0) { vL = 0.f; vR = 0.f; }
  pooled[k * 512 + c] = vL;
  pooled[k * 512 + 256 + c] = vR;
}

__global__ __launch_bounds__(256) void colnorm_kernel(const float* __restrict__ pooled,
                                                      float* __restrict__ normsq) {
  int tid = threadIdx.x;
  int rows_per = (NCL + gridDim.x - 1) / gridDim.x;
  int r0 = blockIdx.x * rows_per;
  int r1 = min(r0 + rows_per, NCL);
  float s0 = 0.f, s1 = 0.f;
  for (int r = r0; r < r1; ++r) {
    float a = pooled[(long)r * 512 + tid];
    float b = pooled[(long)r * 512 + 256 + tid];
    s0 = fmaf(a, a, s0);
    s1 = fmaf(b, b, s1);
  }
  atomicAdd(&normsq[tid], s0);
  atomicAdd(&normsq[tid + 256], s1);
}

__global__ __launch_bounds__(256) void normalize_kernel(const float* __restrict__ pooled,
                                                        const float* __restrict__ normsq,
                                                        float* __restrict__ out) {
  long idx = (long)blockIdx.x * 256 + threadIdx.x;
  if (idx < (long)NCL * 512) {
    float nv = normsq[idx & 511];
    out[idx] = pooled[idx] * rsqrtf(nv);
  }
}

extern "C" void kernel_launch(void* const* d_in, const int* in_sizes, int n_in,
                              void* d_out, int out_size, void* d_ws, size_t ws_size,
                              hipStream_t stream) {
  const float* x0 = (const float*)d_in[0];
  const int* ei = (const int*)d_in[1];
  const int* cl = (const int*)d_in[2];

  const float* W1f[3]; const float* b1f[3]; const float* gf[3];
  const float* bef[3]; const float* W2f[3]; const float* b2f[3];
  for (int i = 0; i < 3; ++i) {
    W1f[i] = (const float*)d_in[3 + 6 * i + 0];
    b1f[i] = (const float*)d_in[3 + 6 * i + 1];
    gf[i]  = (const float*)d_in[3 + 6 * i + 2];
    bef[i] = (const float*)d_in[3 + 6 * i + 3];
    W2f[i] = (const float*)d_in[3 + 6 * i + 4];
    b2f[i] = (const float*)d_in[3 + 6 * i + 5];
  }

  char* ws = (char*)d_ws;
  size_t off = 0;
  auto take = [&](size_t bytes) {
    size_t o = off; off = (off + bytes + 255) & ~(size_t)255; return o;
  };
  // region R1: x1 [N,128] bf16 (layer0/1), later x3c [N,256] bf16 (x1 dead
  // once mlp<128> has consumed it; mlp<256> then writes x3c here).
  unsigned short* x1 = (unsigned short*)(ws + take((size_t)NN * 256 * 2));
  unsigned short* x3c = x1;
  // region R2: x2 [N,256] bf16 (layers 1/2), later pooled [NC,512] fp32
  // (x2 dead after mlp<256> reads it; poolfuse writes pooled here).
  unsigned short* x2 = (unsigned short*)(ws + take((size_t)NN * 256 * 2));
  float* pooled = (float*)x2;
  // bucket must stay live through poolfuse -> own region (NOT aliased).
  int* bucket = (int*)(ws + take((size_t)NN * CAPN * 4));
  int* cbucket = (int*)(ws + take((size_t)NCL * CAPC * 4));
  int* zero_base = (int*)(ws + take((size_t)(NN + NCL + 512) * 4));
  int* cnt = zero_base;
  int* ccnt = zero_base + NN;
  float* normsq = (float*)(zero_base + NN + NCL);

  int Cs[3] = {64, 128, 256};
  unsigned short *W1T[3], *W2T[3];
  for (int i = 0; i < 3; ++i) {
    W1T[i] = (unsigned short*)(ws + take((size_t)64 * Cs[i] * 2));
    W2T[i] = (unsigned short*)(ws + take((size_t)Cs[i] * 64 * 2));
  }

  if (off > ws_size) return;  // clean-fail guard

  WtPack wp;
  for (int i = 0; i < 3; ++i) {
    wp.d[2 * i + 0] = { W1f[i], W1T[i], Cs[i], 64 };
    wp.d[2 * i + 1] = { W2f[i], W2T[i], 64, Cs[i] };
  }

  int zn = NN + NCL + 512;
  int zblocks = (zn + 255) / 256;
  prep_kernel<<<zblocks + 32, 256, 0, stream>>>(zero_base, zn, zblocks, wp);

  int ntiles = NN / 16;            // 6250 (exact: no tail)
  int nblk = (ntiles / 2 + 3) / 4; // 782 mlp blocks x 4 waves x 2 tiles
  int nwork = NE / 4 + NN / 4;
  int sblocks = (nwork + 255) / 256;  // 879 scatter blocks

  // fused: scatter (blocks [0,sblocks)) + mlp layer 0 (rest)
  mlp_mfma_kernel<64, true, true><<<sblocks + nblk, 256, 0, stream>>>(
      x0, W1T[0], b1f[0], gf[0], bef[0], W2T[0], b2f[0], x1, 128, ntiles,
      sblocks, ei, cnt, bucket, cl, ccnt, cbucket);
  aggr_kernel<64><<<NN / 32, 256, 0, stream>>>(cnt, bucket, x1);
  mlp_mfma_kernel<128, false, false><<<nblk, 256, 0, stream>>>(
      x1, W1T[1], b1f[1], gf[1], bef[1], W2T[1], b2f[1], x2, 256, ntiles,
      0, nullptr, nullptr, nullptr, nullptr, nullptr, nullptr);
  aggr_kernel<128><<<NN / 16, 256, 0, stream>>>(cnt, bucket, x2);
  // layer 2 writes compact h3 [N,256] (no aggr half materialized)
  mlp_mfma_kernel<256, false, false><<<nblk, 256, 0, stream>>>(
      x2, W1T[2], b1f[2], gf[2], bef[2], W2T[2], b2f[2], x3c, 256, ntiles,
      0, nullptr, nullptr, nullptr, nullptr, nullptr, nullptr);

  // fused aggr<256> + cluster max-pool, one block per cluster
  poolfuse_kernel<<<NCL, 256, 0, stream>>>(ccnt, cbucket, cnt, bucket, x3c, pooled);
  colnorm_kernel<<<128, 256, 0, stream>>>(pooled, normsq);
  normalize_kernel<<<((long)NCL * 512 + 255) / 256, 256, 0, stream>>>(pooled, normsq, (float*)d_out);
}